// Round 10
// baseline (187.536 us; speedup 1.0000x reference)
//
#include <hip/hip_runtime.h>
#include <hip/hip_bf16.h>

#define BATCH 8
#define NPTS 2048
#define LATENT 128

typedef __attribute__((ext_vector_type(8))) short short8;
typedef __attribute__((ext_vector_type(4))) float f32x4;

__device__ __forceinline__ ushort f2bf(float f) {
  unsigned int b = __float_as_uint(f);
  b += 0x7FFF + ((b >> 16) & 1);
  return (ushort)(b >> 16);
}
__device__ __forceinline__ float bf2f(ushort u) {
  return __uint_as_float(((unsigned int)u) << 16);
}
// packed bf16 convert (v_cvt_pk_bf16_f32 on gfx950), RNE — same as f2bf
__device__ __forceinline__ unsigned int pkbf(float a, float b) {
  __hip_bfloat162 h = __float22bfloat162_rn(make_float2(a, b));
  return *(unsigned int*)&h;
}

// log2(e) and sqrt(2*log2(e)) — points are stored in exp2-space
#define L2E 1.4426950408889634f
#define SC2 1.6986436f

// ---------------------------------------------------------------------------
// setup: bid 0..7 = prep (centroid + pnt), 8..9 = WT1, 10..17 = WT2,
//        18..25 = WzT. WT[n][k] = bf16(W[k][n]).
// pnt[b][n] = (SC2*xc, -|xc|^2*L2E): pi.w+pj.w+dot(pi.xyz,pj.xyz) = -L2E*dist.
// ---------------------------------------------------------------------------
__device__ __forceinline__ void wtrans_tile(const float* __restrict__ W,
    ushort* __restrict__ WT, int K, int N, int n0, int k0, int tid) {
  __shared__ ushort s[64][72];
  for (int i = tid; i < 64 * 64; i += 256) {
    const int kl = i >> 6, nl = i & 63;
    s[kl][nl] = f2bf(W[(size_t)(k0 + kl) * N + n0 + nl]);
  }
  __syncthreads();
  for (int i = tid; i < 64 * 64; i += 256) {
    const int nl = i >> 6, kl = i & 63;
    WT[(size_t)(n0 + nl) * K + k0 + kl] = s[kl][nl];
  }
}

__global__ __launch_bounds__(256) void setup_kernel(const float* __restrict__ x,
    const float* __restrict__ mask, float4* __restrict__ pnt,
    const float* __restrict__ W1, ushort* __restrict__ WT1,
    const float* __restrict__ W2, ushort* __restrict__ WT2,
    const float* __restrict__ Wz, ushort* __restrict__ WzT) {
  const int bid = blockIdx.x;
  const int tid = threadIdx.x;
  if (bid >= 8) {
    if (bid < 10) wtrans_tile(W1, WT1, 64, 128, (bid - 8) * 64, 0, tid);
    else if (bid < 18) {
      const int idx = bid - 10;
      wtrans_tile(W2, WT2, 128, 256, (idx & 3) * 64, (idx >> 2) * 64, tid);
    } else {
      const int idx = bid - 18;
      wtrans_tile(Wz, WzT, 256, 128, (idx & 1) * 64, (idx >> 1) * 64, tid);
    }
    return;
  }
  const int b = bid;
  const float* xb = x + (size_t)b * NPTS * 3;
  const float* mb = mask + (size_t)b * NPTS;
  float s0 = 0.f, s1 = 0.f, s2 = 0.f, c = 0.f;
  for (int n = tid; n < NPTS; n += 256) {
    float m = mb[n];
    s0 += xb[n * 3 + 0] * m;
    s1 += xb[n * 3 + 1] * m;
    s2 += xb[n * 3 + 2] * m;
    c += m;
  }
  __shared__ float red[4][256];
  red[0][tid] = s0; red[1][tid] = s1; red[2][tid] = s2; red[3][tid] = c;
  __syncthreads();
  for (int off = 128; off > 0; off >>= 1) {
    if (tid < off) {
      red[0][tid] += red[0][tid + off];
      red[1][tid] += red[1][tid + off];
      red[2][tid] += red[2][tid + off];
      red[3][tid] += red[3][tid + off];
    }
    __syncthreads();
  }
  const float cnt = fmaxf(red[3][0], 1.0f);
  const float c0 = red[0][0] / cnt, c1 = red[1][0] / cnt, c2 = red[2][0] / cnt;
  float4* pb = pnt + (size_t)b * NPTS;
  for (int n = tid; n < NPTS; n += 256) {
    const float a0 = xb[n * 3 + 0] - c0;
    const float a1 = xb[n * 3 + 1] - c1;
    const float a2 = xb[n * 3 + 2] - c2;
    pb[n] = make_float4(a0 * SC2, a1 * SC2, a2 * SC2,
                        -(a0 * a0 + a1 * a1 + a2 * a2) * L2E);
  }
}

// ---------------------------------------------------------------------------
// layer 0 fused: aggregation (D=3, VALU, 8-way j-split) + dense 3->64 +
// LN + swish + transposed bf16 write h1T[b][d][n]. 64 rows/block, 512 thr.
// ---------------------------------------------------------------------------
__global__ __launch_bounds__(512) void layer0_kernel(
    const float4* __restrict__ pnt, const float* __restrict__ W,
    const float* __restrict__ bias, const float* __restrict__ g,
    const float* __restrict__ be, ushort* __restrict__ hout) {
  const int b = blockIdx.y;
  const int i0 = blockIdx.x * 64;
  const int tid = threadIdx.x;
  const int il = tid & 63, part = tid >> 6;   // 8 j-parts
  const float4* pb = pnt + (size_t)b * NPTS;
  const float4 pi = pb[i0 + il];
  float a0 = 0.f, a1 = 0.f, a2 = 0.f, dn = 0.f;
#pragma unroll 8
  for (int j = part * 256; j < part * 256 + 256; j++) {
    const float4 pj = pb[j];
    float arg = pi.w + pj.w;
    arg = fmaf(pi.x, pj.x, arg);
    arg = fmaf(pi.y, pj.y, arg);
    arg = fmaf(pi.z, pj.z, arg);
    const float w = __builtin_amdgcn_exp2f(arg);
    a0 = fmaf(w, pj.x, a0);
    a1 = fmaf(w, pj.y, a1);
    a2 = fmaf(w, pj.z, a2);
    dn += w;
  }
  __shared__ float4 sred[8][64];
  __shared__ float srow[64 * 3];
  __shared__ ushort lt[64][64];
  sred[part][il] = make_float4(a0, a1, a2, dn);
  __syncthreads();
  if (tid < 64) {
    float A0 = 0.f, A1 = 0.f, A2 = 0.f, DN = 0.f;
#pragma unroll
    for (int p = 0; p < 8; p++) {
      const float4 r = sred[p][tid];
      A0 += r.x; A1 += r.y; A2 += r.z; DN += r.w;
    }
    const float inv = 1.0f / (DN * SC2);   // undo SC2 scaling of xyz
    srow[tid * 3 + 0] = A0 * inv;
    srow[tid * 3 + 1] = A1 * inv;
    srow[tid * 3 + 2] = A2 * inv;
  }
  __syncthreads();
  const int wv = tid >> 6, lane = tid & 63;
  const float w0c = W[lane], w1c = W[64 + lane], w2c = W[128 + lane];
  const float gv = g[lane], bev = be[lane], bv = bias[lane];
#pragma unroll
  for (int r = 0; r < 8; r++) {
    const int row = wv * 8 + r;
    float o = bv;
    o = fmaf(srow[row * 3 + 0], w0c, o);
    o = fmaf(srow[row * 3 + 1], w1c, o);
    o = fmaf(srow[row * 3 + 2], w2c, o);
    float m1 = o, m2 = o * o;
#pragma unroll
    for (int off = 32; off > 0; off >>= 1) {
      m1 += __shfl_xor(m1, off, 64);
      m2 += __shfl_xor(m2, off, 64);
    }
    const float mu = m1 / 64.f;
    const float rstd = rsqrtf(m2 / 64.f - mu * mu + 1e-6f);
    const float v = (o - mu) * rstd * gv + bev;
    const float act = v / (1.0f + __expf(-v));
    lt[row][lane] = f2bf(act);
  }
  __syncthreads();
  if (tid < 64) {
    ushort tmp[64];
#pragma unroll
    for (int r = 0; r < 64; r++) tmp[r] = lt[r][tid];
    ushort* dst = hout + ((size_t)b * 64 + tid) * NPTS + i0;
#pragma unroll
    for (int c = 0; c < 8; c++)
      *(uint4*)(dst + c * 8) = *(uint4*)&tmp[c * 8];
  }
}

// ---------------------------------------------------------------------------
// FUSED layer v7 — BARRIER-FREE K-loop:
//  - pnt staged to LDS once (bank-swizzled), single barrier.
//  - B-fragments (hT rows) read DIRECTLY from global/L2 each k-step: each
//    lane's frag is one contiguous 16B load; w-gen VALU covers the latency.
//    No per-tile __syncthreads, no global_load_lds drains — waves decoupled.
//  - wave = j-quarter (512 j, 16 k-steps), all 32 rows per wave (2 A-frags).
//  - epilogue: 4-phase split-K combine in LDS, MFMA dense (bf16 WT),
//    LN + swish; POOL emits mask-weighted column partials.
// ---------------------------------------------------------------------------
template <int DIN, int DOUT, bool POOL, int MINW>
__global__ __launch_bounds__(256, MINW) void fused_layer(
    const float4* __restrict__ pnt, const ushort* __restrict__ hT,
    const ushort* __restrict__ WT, const float* __restrict__ bias,
    const float* __restrict__ g, const float* __restrict__ be,
    ushort* __restrict__ hout, const float* __restrict__ mask,
    float* __restrict__ partial) {
  constexpr int NT = DIN / 16;
  constexpr int QJ = NPTS / 4;          // j span per wave
  constexpr int KS = QJ / 32;           // 16 k-steps
  constexpr int NCOL = DOUT / 32;       // dense col-tiles per wave
  constexpr int PS = DIN + 8;           // srow pitch (ushorts)
  constexpr int PN = DIN + 4;           // snum pitch (floats)
  constexpr int SPNT_B = NPTS * 16;     // 32 KB pnt (swizzled)
  constexpr int SNUM_B = 32 * PN * 4;
  constexpr int OFF_SROW = SNUM_B;
  constexpr int OFF_SDEN = OFF_SROW + 32 * PS * 2;
  constexpr int OFF_SINV = OFF_SDEN + 128;
  constexpr int OFF_SSTAT = OFF_SINV + 128;
  constexpr int EPI_B = OFF_SSTAT + 512;
  constexpr int SMEM_B = SPNT_B > EPI_B ? SPNT_B : EPI_B;
  __shared__ __align__(16) char smem[SMEM_B];
  float4* sp = (float4*)smem;

  const int b = blockIdx.y;
  const int i0 = blockIdx.x * 32;
  const int tid = threadIdx.x;
  const int wv = tid >> 6, lane = tid & 63;
  const int m = lane & 15, q = lane >> 4;
  const float4* pb = pnt + (size_t)b * NPTS;
  const ushort* hb = hT + (size_t)b * DIN * NPTS;

  // stage pnt once, bank-swizzled: phys = (j&~31) | ((j&7)<<2) | ((j>>3)&3)
#pragma unroll
  for (int i = 0; i < NPTS / 256; i++) {
    const int j = i * 256 + tid;
    const int phys = (j & ~31) | (((j & 7) << 2) | ((j >> 3) & 3));
    sp[phys] = pb[j];
  }
  const float4 pi0 = pb[i0 + m];        // A-rows 0..15
  const float4 pi1 = pb[i0 + 16 + m];   // A-rows 16..31
  __syncthreads();

  f32x4 acc0[NT], acc1[NT];
#pragma unroll
  for (int nt = 0; nt < NT; nt++)
#pragma unroll
    for (int e = 0; e < 4; e++) { acc0[nt][e] = 0.f; acc1[nt][e] = 0.f; }
  float dacc0 = 0.f, dacc1 = 0.f;

  const int jq = wv * QJ;   // this wave's j range

  for (int k = 0; k < KS; k++) {
    const int j0 = jq + k * 32;
    // B-fragments straight from global (L2-hot): lane (m,q) reads 16B of
    // row d=nt*16+m at j0+q*8
    short8 bq[NT];
#pragma unroll
    for (int nt = 0; nt < NT; nt++)
      bq[nt] = *(const short8*)(hb + (size_t)(nt * 16 + m) * NPTS + j0 + q * 8);
    // w-gen from LDS pnt (covers the global-load latency)
    float w0a[8], w1a[8];
#pragma unroll
    for (int jj = 0; jj < 8; jj++) {
      const float4 pj = sp[j0 + ((jj << 2) | q)];   // swizzled: conflict-free
      float a0 = pi0.w + pj.w;
      a0 = fmaf(pi0.x, pj.x, a0);
      a0 = fmaf(pi0.y, pj.y, a0);
      a0 = fmaf(pi0.z, pj.z, a0);
      float a1 = pi1.w + pj.w;
      a1 = fmaf(pi1.x, pj.x, a1);
      a1 = fmaf(pi1.y, pj.y, a1);
      a1 = fmaf(pi1.z, pj.z, a1);
      w0a[jj] = __builtin_amdgcn_exp2f(a0);   // exp(-dist)
      w1a[jj] = __builtin_amdgcn_exp2f(a1);
      dacc0 += w0a[jj]; dacc1 += w1a[jj];
    }
    unsigned int au0[4], au1[4];
#pragma unroll
    for (int p = 0; p < 4; p++) {
      au0[p] = pkbf(w0a[2 * p], w0a[2 * p + 1]);
      au1[p] = pkbf(w1a[2 * p], w1a[2 * p + 1]);
    }
    const short8 af0 = *(short8*)au0;
    const short8 af1 = *(short8*)au1;
#pragma unroll
    for (int nt = 0; nt < NT; nt++) {
      acc0[nt] = __builtin_amdgcn_mfma_f32_16x16x32_bf16(af0, bq[nt], acc0[nt], 0, 0, 0);
      acc1[nt] = __builtin_amdgcn_mfma_f32_16x16x32_bf16(af1, bq[nt], acc1[nt], 0, 0, 0);
    }
  }
  __syncthreads();   // all waves done with sp; epilogue aliases it

  // ---- 1-slot 4-phase split-K combine in LDS ----
  float* snum = (float*)smem;                    // [32][PN]
  ushort* srow = (ushort*)(smem + OFF_SROW);     // [32][PS]
  float* sden = (float*)(smem + OFF_SDEN);
  float* sinv = (float*)(smem + OFF_SINV);
  float* sstat = (float*)(smem + OFF_SSTAT);

  dacc0 += __shfl_xor(dacc0, 16, 64);
  dacc0 += __shfl_xor(dacc0, 32, 64);
  dacc1 += __shfl_xor(dacc1, 16, 64);
  dacc1 += __shfl_xor(dacc1, 32, 64);
  for (int p = 0; p < 4; p++) {
    if (wv == p) {
      if (p == 0) {
#pragma unroll
        for (int nt = 0; nt < NT; nt++)
#pragma unroll
          for (int r = 0; r < 4; r++) {
            snum[(q * 4 + r) * PN + nt * 16 + m] = acc0[nt][r];
            snum[(16 + q * 4 + r) * PN + nt * 16 + m] = acc1[nt][r];
          }
        if (q == 0) { sden[m] = dacc0; sden[16 + m] = dacc1; }
      } else {
#pragma unroll
        for (int nt = 0; nt < NT; nt++)
#pragma unroll
          for (int r = 0; r < 4; r++) {
            snum[(q * 4 + r) * PN + nt * 16 + m] += acc0[nt][r];
            snum[(16 + q * 4 + r) * PN + nt * 16 + m] += acc1[nt][r];
          }
        if (q == 0) { sden[m] += dacc0; sden[16 + m] += dacc1; }
      }
    }
    __syncthreads();
  }
  if (tid < 32) sinv[tid] = 1.0f / sden[tid];
  __syncthreads();
  for (int idx = tid; idx < 32 * (DIN / 2); idx += 256) {
    const int r = idx / (DIN / 2), c2 = idx % (DIN / 2);
    const float v0 = snum[r * PN + 2 * c2] * sinv[r];
    const float v1 = snum[r * PN + 2 * c2 + 1] * sinv[r];
    *(unsigned int*)&srow[r * PS + 2 * c2] = pkbf(v0, v1);
  }
  __syncthreads();

  // ---- dense via MFMA: rows (wv>>1)*16.., col-half (wv&1) ----
  const int rg2 = wv >> 1, ch = wv & 1;
  short8 afrag[DIN / 32];
#pragma unroll
  for (int kt = 0; kt < DIN / 32; kt++)
    afrag[kt] = *(const short8*)&srow[(rg2 * 16 + m) * PS + kt * 32 + q * 8];
  f32x4 oacc[NCOL];
#pragma unroll
  for (int c = 0; c < NCOL; c++)
#pragma unroll
    for (int e = 0; e < 4; e++) oacc[c][e] = 0.f;
#pragma unroll
  for (int c = 0; c < NCOL; c++) {
    const int n0 = (ch * NCOL + c) * 16;
#pragma unroll
    for (int kt = 0; kt < DIN / 32; kt++) {
      const short8 bfrag = *(const short8*)(WT + (size_t)(n0 + m) * DIN + kt * 32 + q * 8);
      oacc[c] = __builtin_amdgcn_mfma_f32_16x16x32_bf16(afrag[kt], bfrag, oacc[c], 0, 0, 0);
    }
  }

  // ---- LN stats across both col-halves via LDS ----
  float bcol[NCOL];
#pragma unroll
  for (int c = 0; c < NCOL; c++) bcol[c] = bias[(ch * NCOL + c) * 16 + m];
#pragma unroll
  for (int r = 0; r < 4; r++) {
    float m1 = 0.f, m2 = 0.f;
#pragma unroll
    for (int c = 0; c < NCOL; c++) {
      const float v = oacc[c][r] + bcol[c];
      m1 += v; m2 += v * v;
    }
#pragma unroll
    for (int off = 8; off > 0; off >>= 1) {
      m1 += __shfl_xor(m1, off, 64);
      m2 += __shfl_xor(m2, off, 64);
    }
    if (m == 0) {
      const int row = rg2 * 16 + q * 4 + r;
      sstat[(row * 2 + ch) * 2 + 0] = m1;
      sstat[(row * 2 + ch) * 2 + 1] = m2;
    }
  }
  __syncthreads();

  ushort* lt = (ushort*)smem;   // [32][DOUT], aliases dead snum (TOUT path)
  float* spl = (float*)smem;    // [2][DOUT] (POOL path)
  float pacc[NCOL];
  if (POOL) {
#pragma unroll
    for (int c = 0; c < NCOL; c++) pacc[c] = 0.f;
  }
#pragma unroll
  for (int r = 0; r < 4; r++) {
    const int row = rg2 * 16 + q * 4 + r;
    const float m1 = sstat[(row * 2 + 0) * 2 + 0] + sstat[(row * 2 + 1) * 2 + 0];
    const float m2 = sstat[(row * 2 + 0) * 2 + 1] + sstat[(row * 2 + 1) * 2 + 1];
    const float mu = m1 / DOUT;
    const float rstd = rsqrtf(m2 / DOUT - mu * mu + 1e-6f);
    float mval = 0.f;
    if (POOL) mval = mask[(size_t)b * NPTS + i0 + row];
#pragma unroll
    for (int c = 0; c < NCOL; c++) {
      const int dco = (ch * NCOL + c) * 16 + m;
      const float v = (oacc[c][r] + bcol[c] - mu) * rstd * g[dco] + be[dco];
      const float act = v / (1.0f + __expf(-v));
      if (POOL) pacc[c] = fmaf(act, mval, pacc[c]);
      else lt[row * DOUT + dco] = f2bf(act);
    }
  }
  if (POOL) {
#pragma unroll
    for (int c = 0; c < NCOL; c++) {
      float v = pacc[c];
      v += __shfl_xor(v, 16, 64);
      v += __shfl_xor(v, 32, 64);   // sum over q -> this wave's 16 rows
      if (q == 0) spl[rg2 * DOUT + (ch * NCOL + c) * 16 + m] = v;
    }
    __syncthreads();
    if (tid < DOUT)
      partial[((size_t)b * (NPTS / 32) + blockIdx.x) * DOUT + tid] =
          spl[tid] + spl[DOUT + tid];
  } else {
    __syncthreads();
    if (tid < DOUT) {
      ushort tmp[32];
#pragma unroll
      for (int r = 0; r < 32; r++) tmp[r] = lt[r * DOUT + tid];
      ushort* dst = hout + ((size_t)b * DOUT + tid) * NPTS + i0;
#pragma unroll
      for (int c = 0; c < 4; c++)
        *(uint4*)(dst + c * 8) = *(uint4*)&tmp[c * 8];
    }
  }
}

// ---------------------------------------------------------------------------
// readout: reduce 64 partial rows/batch, /count, Dense(256->128) with
// bf16 WzT[n][k] (contiguous dwordx4 loads, dot split across 2 half-waves).
// ---------------------------------------------------------------------------
__global__ __launch_bounds__(256) void readout_kernel(
    const float* __restrict__ partial, const float* __restrict__ mask,
    const ushort* __restrict__ WzT, const float* __restrict__ bz,
    float* __restrict__ out) {
  const int b = blockIdx.x;
  const int tid = threadIdx.x;
  const float* pb = partial + (size_t)b * (NPTS / 32) * 256;
  float s0 = 0.f, s1 = 0.f, s2 = 0.f, s3 = 0.f;
#pragma unroll 4
  for (int p = 0; p < NPTS / 32; p += 4) {
    s0 += pb[(size_t)(p + 0) * 256 + tid];
    s1 += pb[(size_t)(p + 1) * 256 + tid];
    s2 += pb[(size_t)(p + 2) * 256 + tid];
    s3 += pb[(size_t)(p + 3) * 256 + tid];
  }
  const float s = (s0 + s1) + (s2 + s3);
  const float* mb = mask + (size_t)b * NPTS;
  float c = 0.f;
  for (int n = tid; n < NPTS; n += 256) c += mb[n];
  __shared__ float red[256];
  red[tid] = c;
  __syncthreads();
  for (int off = 128; off > 0; off >>= 1) {
    if (tid < off) red[tid] += red[tid + off];
    __syncthreads();
  }
  const float cnt = fmaxf(red[0], 1.0f);
  __shared__ float gf[256];
  gf[tid] = s / cnt;
  __syncthreads();
  const int col = tid & 127, part = tid >> 7;   // split dot over 2 groups
  float z = 0.f;
  const ushort* wr = WzT + (size_t)col * 256 + part * 128;
  const float* gp = gf + part * 128;
#pragma unroll 4
  for (int d = 0; d < 128; d += 8) {
    const short8 w8 = *(const short8*)(wr + d);
#pragma unroll
    for (int e = 0; e < 8; e++)
      z = fmaf(gp[d + e], bf2f((ushort)w8[e]), z);
  }
  __shared__ float zred[256];
  zred[tid] = z;
  __syncthreads();
  if (tid < LATENT)
    out[(size_t)b * LATENT + tid] = bz[tid] + zred[tid] + zred[128 + tid];
}

// ---------------------------------------------------------------------------
extern "C" void kernel_launch(void* const* d_in, const int* in_sizes, int n_in,
                              void* d_out, int out_size, void* d_ws, size_t ws_size,
                              hipStream_t stream) {
  const float* x    = (const float*)d_in[0];
  const float* mask = (const float*)d_in[1];
  const float* W0   = (const float*)d_in[2];
  const float* b0   = (const float*)d_in[3];
  const float* g0   = (const float*)d_in[4];
  const float* be0  = (const float*)d_in[5];
  const float* W1   = (const float*)d_in[6];
  const float* b1   = (const float*)d_in[7];
  const float* g1   = (const float*)d_in[8];
  const float* be1  = (const float*)d_in[9];
  const float* W2   = (const float*)d_in[10];
  const float* b2   = (const float*)d_in[11];
  const float* g2   = (const float*)d_in[12];
  const float* be2  = (const float*)d_in[13];
  const float* Wz   = (const float*)d_in[14];
  const float* bz   = (const float*)d_in[15];
  float* out = (float*)d_out;

  // workspace layout (bytes, 16B-aligned regions)
  char* ws = (char*)d_ws;
  float4* pnt     = (float4*)(ws);             // 262144
  ushort* h1T     = (ushort*)(ws + 262144);    // 2097152
  ushort* h2T     = (ushort*)(ws + 2359296);   // 4194304
  float*  partial = (float*)(ws + 6553600);    // 8*64*256*4 = 524288
  ushort* WT1     = (ushort*)(ws + 7077888);   // 16384
  ushort* WT2     = (ushort*)(ws + 7094272);   // 65536
  ushort* WzT     = (ushort*)(ws + 7159808);   // 128*256*2 = 65536
  // total ~7.2 MB

  // prep + all W transposes in one launch
  setup_kernel<<<dim3(26), dim3(256), 0, stream>>>(
      x, mask, pnt, W1, WT1, W2, WT2, Wz, WzT);

  // layer 0: agg (D=3) + dense 3->64 + LN + swish, fused
  layer0_kernel<<<dim3(NPTS / 64, BATCH), dim3(512), 0, stream>>>(
      pnt, W0, b0, g0, be0, h1T);

  // layer 1 (64 -> 128): fused MFMA agg + MFMA dense + LN + swish
  fused_layer<64, 128, false, 4><<<dim3(NPTS / 32, BATCH), dim3(256), 0, stream>>>(
      pnt, h1T, WT1, b1, g1, be1, h2T, nullptr, nullptr);

  // layer 2 (128 -> 256): fused + masked-sum pooling
  fused_layer<128, 256, true, 3><<<dim3(NPTS / 32, BATCH), dim3(256), 0, stream>>>(
      pnt, h2T, WT2, b2, g2, be2, nullptr, mask, partial);

  // readout
  readout_kernel<<<dim3(BATCH), dim3(256), 0, stream>>>(partial, mask, WzT, bz, out);
}